// Round 18
// baseline (995.710 us; speedup 1.0000x reference)
//
#include <hip/hip_runtime.h>

#define NN_ 131072      // T*N
#define T_ 64
#define N_ 2048
#define E_ 2097152
#define FIN_ 16

typedef unsigned short ushort_t;
typedef unsigned int uint_t;

// Clobber-free LDS barrier: no vmcnt drain.
__device__ __forceinline__ void lbar2() {
  __builtin_amdgcn_sched_barrier(0);
  asm volatile("s_waitcnt lgkmcnt(0)");
  __builtin_amdgcn_s_barrier();
  __builtin_amdgcn_sched_barrier(0);
}

__device__ __forceinline__ float bf2f(ushort_t u) {
  return __uint_as_float(((uint_t)u) << 16);
}
__device__ __forceinline__ ushort_t f2bf(float f) {
  uint_t b = __float_as_uint(f);
  b += 0x7fffu + ((b >> 16) & 1u);   // round-to-nearest-even
  return (ushort_t)(b >> 16);
}

#if __has_builtin(__builtin_amdgcn_fdot2)
#define HAVE_DOT2 1
typedef __fp16 half2v __attribute__((ext_vector_type(2)));
__device__ __forceinline__ half2v u2h(uint_t u) { union { uint_t u; half2v h; } x; x.u = u; return x.h; }
__device__ __forceinline__ uint_t h2u(half2v h) { union { uint_t u; half2v h; } x; x.h = h; return x.u; }
#else
#define HAVE_DOT2 0
#endif

// ---------------- zero cnt ----------------
__global__ void k_zero(uint_t* __restrict__ cnt) {
  int i = blockIdx.x * 256 + threadIdx.x;
  if (i < NN_) cnt[i] = 0u;
}

// ---------------- histogram of col (1 edge/thread — measured best) -----------
__global__ void k_hist(const int* __restrict__ col, uint_t* __restrict__ cnt) {
  int e = blockIdx.x * 256 + threadIdx.x;
  atomicAdd(&cnt[col[e]], 1u);
}

// ---------------- dinv from counts (+1 self loop) ----------------
__global__ void k_dinvc(const uint_t* __restrict__ cnt, float* __restrict__ dinv) {
  int v = blockIdx.x * 256 + threadIdx.x;
  dinv[v] = rsqrtf((float)cnt[v] + 1.f);
}

// ---------------- per-256-chunk sums ----------------
__global__ void k_bsum(const uint_t* __restrict__ cnt, uint_t* __restrict__ bsum) {
  int t = threadIdx.x;
  uint_t v = cnt[blockIdx.x * 256 + t];
  for (int off = 32; off; off >>= 1) v += __shfl_down(v, off);
  __shared__ uint_t s4[4];
  if ((t & 63) == 0) s4[t >> 6] = v;
  __syncthreads();
  if (t == 0) bsum[blockIdx.x] = s4[0] + s4[1] + s4[2] + s4[3];
}

// ---------------- exclusive scan of 512 chunk sums (1 block) ----------------
__global__ void k_scan512(uint_t* __restrict__ bsum) {
  __shared__ uint_t sd[512];
  int t = threadIdx.x;
  uint_t v = bsum[t];
  sd[t] = v;
  __syncthreads();
  for (int off = 1; off < 512; off <<= 1) {
    uint_t x = (t >= off) ? sd[t - off] : 0u;
    __syncthreads();
    sd[t] += x;
    __syncthreads();
  }
  bsum[t] = sd[t] - v;   // exclusive
}

// ---------------- per-chunk exclusive scan + chunk offset ----------------
__global__ void k_scanadd(const uint_t* __restrict__ cnt, const uint_t* __restrict__ bsum,
                          uint_t* __restrict__ start, uint_t* __restrict__ cursor) {
  int t = threadIdx.x;
  int i = blockIdx.x * 256 + t;
  uint_t v = cnt[i];
  __shared__ uint_t sd[256];
  sd[t] = v;
  __syncthreads();
  for (int off = 1; off < 256; off <<= 1) {
    uint_t x = (t >= off) ? sd[t - off] : 0u;
    __syncthreads();
    sd[t] += x;
    __syncthreads();
  }
  uint_t excl = sd[t] - v + bsum[blockIdx.x];
  start[i] = excl;
  cursor[i] = excl;
  if (i == NN_ - 1) start[NN_] = E_;
}

// ---------------- counting-sort placement (1 edge/thread — measured best) -----
__global__ void k_place(const int* __restrict__ row, const int* __restrict__ col,
                        uint_t* __restrict__ cursor, int* __restrict__ srow) {
  int e = blockIdx.x * 256 + threadIdx.x;
  int c = col[e];
  uint_t pos = atomicAdd(&cursor[c], 1u);
  srow[pos] = row[e];
}

// ---------------- GEMM (NN x K) @ (K x 64), dinv-prescaled, bf16 out ---------
template <int K, bool RELU_IN>
__global__ void k_gemm(const float* __restrict__ X, const float* __restrict__ W,
                       const float* __restrict__ bin, const float* __restrict__ dinv,
                       ushort_t* __restrict__ xws) {
  __shared__ float xs[4 * K];
  const int tid = threadIdx.x;
  const int v0 = blockIdx.x * 4;
  for (int t = tid; t < 4 * K; t += 256) {
    float v = X[(size_t)v0 * K + t];
    if (RELU_IN) v = fmaxf(v + bin[t & (K - 1)], 0.f);
    xs[t] = v;
  }
  __syncthreads();
  const int v = v0 + (tid >> 6);
  const int j = tid & 63;
  const float* xr = &xs[(tid >> 6) * K];
  float acc = 0.f;
#pragma unroll
  for (int k = 0; k < K; ++k) acc = fmaf(xr[k], W[k * 64 + j], acc);
  xws[(size_t)v * 64 + j] = f2bf(dinv[v] * acc);
}

// ---------------- column-gather aggregation (bf16 gathers, 8-way ILP) ---------
__global__ void k_colagg(const int* __restrict__ srow, const uint_t* __restrict__ start,
                         const float* __restrict__ dinv, const ushort_t* __restrict__ xws,
                         float* __restrict__ agg) {
  int c = blockIdx.x * 4 + (threadIdx.x >> 6);
  int lane = threadIdx.x & 63;
  uint_t s = start[c], e = start[c + 1];
  float a0 = bf2f(xws[(size_t)c * 64 + lane]);   // self loop
  float a1 = 0.f, a2 = 0.f, a3 = 0.f;
  float a4 = 0.f, a5 = 0.f, a6 = 0.f, a7 = 0.f;
  uint_t i = s;
  for (; i + 8 <= e; i += 8) {
    int r0 = srow[i],     r1 = srow[i + 1], r2 = srow[i + 2], r3 = srow[i + 3];
    int r4 = srow[i + 4], r5 = srow[i + 5], r6 = srow[i + 6], r7 = srow[i + 7];
    a0 += bf2f(xws[(size_t)r0 * 64 + lane]);
    a1 += bf2f(xws[(size_t)r1 * 64 + lane]);
    a2 += bf2f(xws[(size_t)r2 * 64 + lane]);
    a3 += bf2f(xws[(size_t)r3 * 64 + lane]);
    a4 += bf2f(xws[(size_t)r4 * 64 + lane]);
    a5 += bf2f(xws[(size_t)r5 * 64 + lane]);
    a6 += bf2f(xws[(size_t)r6 * 64 + lane]);
    a7 += bf2f(xws[(size_t)r7 * 64 + lane]);
  }
  for (; i < e; ++i) a0 += bf2f(xws[(size_t)srow[i] * 64 + lane]);
  agg[(size_t)c * 64 + lane] =
      dinv[c] * (((a0 + a1) + (a2 + a3)) + ((a4 + a5) + (a6 + a7)));
}

// ---------------- gate-preactivation GEMM (f16 dot2, bf16 out) ----------------
__global__ __launch_bounds__(256) void k_gates(
    const float* __restrict__ A, const float* __restrict__ b2,
    const float* __restrict__ WihF, const float* __restrict__ bihF,
    const float* __restrict__ bhhF,
    const float* __restrict__ WihB, const float* __restrict__ bihB,
    const float* __restrict__ bhhB,
    ushort_t* __restrict__ gx) {
  const int dir = blockIdx.x >> 11;
  const int v0 = (blockIdx.x & 2047) * 64;
  const float* Wih = dir ? WihB : WihF;
  const float* bih = dir ? bihB : bihF;
  const float* bhh = dir ? bhhB : bhhF;
  const int t = threadIdx.x;
  const float bias = bih[t] + bhh[t];

#if HAVE_DOT2
  half2v wp[32];
#pragma unroll
  for (int k4 = 0; k4 < 16; ++k4) {
    float4 f4 = *reinterpret_cast<const float4*>(&Wih[(size_t)t * 64 + 4 * k4]);
    wp[2 * k4]     = __builtin_amdgcn_cvt_pkrtz(f4.x, f4.y);
    wp[2 * k4 + 1] = __builtin_amdgcn_cvt_pkrtz(f4.z, f4.w);
  }
  __shared__ __align__(16) uint_t xs2[64 * 32];   // f16-pair rows, 8 KB
  const float2* A2 = reinterpret_cast<const float2*>(A + (size_t)v0 * 64);
#pragma unroll
  for (int u = 0; u < 8; ++u) {
    int pi = u * 256 + t;
    float2 f = A2[pi];
    int d0 = (2 * pi) & 63;
    float q0 = fmaxf(f.x + b2[d0], 0.f);
    float q1 = fmaxf(f.y + b2[d0 + 1], 0.f);
    xs2[pi] = h2u(__builtin_amdgcn_cvt_pkrtz(q0, q1));
  }
  __syncthreads();
  const uint4* xq = reinterpret_cast<const uint4*>(xs2);
  ushort_t* gp = gx + ((size_t)(dir ? NN_ : 0) + v0) * 256 + t;
  for (int r = 0; r < 64; ++r) {
    float a = bias;
#pragma unroll
    for (int q = 0; q < 8; ++q) {
      uint4 x4 = xq[r * 8 + q];
      a = __builtin_amdgcn_fdot2(wp[4 * q],     u2h(x4.x), a, false);
      a = __builtin_amdgcn_fdot2(wp[4 * q + 1], u2h(x4.y), a, false);
      a = __builtin_amdgcn_fdot2(wp[4 * q + 2], u2h(x4.z), a, false);
      a = __builtin_amdgcn_fdot2(wp[4 * q + 3], u2h(x4.w), a, false);
    }
    gp[(size_t)r * 256] = f2bf(a);
  }
#else
  float w[64];
#pragma unroll
  for (int k = 0; k < 64; k += 4)
    *reinterpret_cast<float4*>(&w[k]) = *reinterpret_cast<const float4*>(&Wih[t * 64 + k]);
  __shared__ float xs[64 * 64];
#pragma unroll
  for (int u = 0; u < 16; ++u) {
    int idx = u * 256 + t;
    xs[idx] = fmaxf(A[(size_t)v0 * 64 + idx] + b2[idx & 63], 0.f);
  }
  __syncthreads();
  ushort_t* gp = gx + ((size_t)(dir ? NN_ : 0) + v0) * 256 + t;
  for (int r = 0; r < 64; ++r) {
    const float* xr = &xs[r * 64];
    float a = bias;
#pragma unroll
    for (int k = 0; k < 64; ++k) a = fmaf(xr[k], w[k], a);
    gp[(size_t)r * 256] = f2bf(a);
  }
#endif
}

// ---------------- persistent LSTM: chunked + 2 waves + ONE barrier/step -------
// P=32 chunks (C=64, W=32 warm-up). Wave 0: sigma(i),sigma(f); wave 1:
// tanh(g),sigma(o). Pairs exchanged via parity-double-buffered sbuf at ONE
// barrier; both waves then compute c,h redundantly (bit-identical FP) and
// write their OWN hsh copy (same-wave in-order DS -> no 2nd barrier).
#define GRP_ 4
#define CHK_P 32
#define CHK_C (N_ / CHK_P)    // 64 steps per chunk
#define CHK_W 32              // warm-up steps

__global__ __launch_bounds__(128, 1) void k_lstm4(
    const ushort_t* __restrict__ gx,
    const float* __restrict__ WhhF, const float* __restrict__ WhhB,
    float* __restrict__ y) {
  const int blk = blockIdx.x;
  const int b     = blk & 63;
  const int dir   = (blk >> 6) & 1;
  const int chunk = blk >> 7;
  const int l   = threadIdx.x & 63;
  const int w   = threadIdx.x >> 6;      // wave id: 0 -> {i,f}, 1 -> {g,o}
  const float* Whh = dir ? WhhB : WhhF;

  const int cstart = chunk * CHK_C;
  const int sw = chunk ? (cstart - CHK_W) : 0;
  const int ngroups = (cstart + CHK_C - sw) / GRP_;
  const int wstart_g = (cstart - sw) / GRP_;   // first group that writes y

#if HAVE_DOT2
  half2v wp[64];
#pragma unroll
  for (int jg = 0; jg < 2; ++jg) {
    const size_t grow = (size_t)((2 * w + jg) * 64 + l) * 64;
#pragma unroll
    for (int k4 = 0; k4 < 16; ++k4) {
      float4 f4 = *reinterpret_cast<const float4*>(&Whh[grow + 4 * k4]);
      wp[jg * 32 + 2 * k4]     = __builtin_amdgcn_cvt_pkrtz(f4.x, f4.y);
      wp[jg * 32 + 2 * k4 + 1] = __builtin_amdgcn_cvt_pkrtz(f4.z, f4.w);
    }
  }
  __shared__ __align__(16) __fp16 hsh[2][64];   // per-wave private h copies
  __shared__ float sbuf[2][2][2][64];           // [parity][wave][slot][lane]
  hsh[w][l] = (__fp16)0.f;     // own-wave init; in-order DS, no barrier needed
  float c = 0.f;

  const long stride = dir ? -256 : 256;
  const long ystr   = dir ? -128 : 128;
  const int sbase = dir ? (N_ - 1 - sw) : sw;
  const ushort_t* p = gx + ((size_t)dir * NN_ + (size_t)b * N_ + sbase) * 256 + 2 * w * 64 + l;
  float* yp = y + ((size_t)b * N_ + sbase) * 128 + (size_t)dir * 64 + l;

  ushort_t zc[GRP_][2], zn[GRP_][2];
#pragma unroll
  for (int i = 0; i < GRP_; ++i) {
    zc[i][0] = p[i * stride];
    zc[i][1] = p[i * stride + 64];
  }
  p += GRP_ * stride;

  const uint4* hsq = reinterpret_cast<const uint4*>(hsh[w]);

  for (int g = 0; g < ngroups; ++g) {
    if (g != ngroups - 1) {
#pragma unroll
      for (int i = 0; i < GRP_; ++i) {
        zn[i][0] = p[i * stride];
        zn[i][1] = p[i * stride + 64];
      }
    }
    p += GRP_ * stride;

    float yv[GRP_];
#pragma unroll
    for (int i = 0; i < GRP_; ++i) {
      const int par = i & 1;
      uint_t hu[32];
#pragma unroll
      for (int q = 0; q < 8; ++q) {         // 8 broadcast b128 reads of own h
        uint4 hq = hsq[q];
        hu[4*q] = hq.x; hu[4*q+1] = hq.y; hu[4*q+2] = hq.z; hu[4*q+3] = hq.w;
      }
      float a0 = bf2f(zc[i][0]), a1 = bf2f(zc[i][1]);
#pragma unroll
      for (int m = 0; m < 32; ++m) {        // 64 fdot2 per wave
        half2v hm = u2h(hu[m]);
        a0 = __builtin_amdgcn_fdot2(wp[m],      hm, a0, false);
        a1 = __builtin_amdgcn_fdot2(wp[32 + m], hm, a1, false);
      }
      float s0v, s1v;
      if (w == 0) {
        s0v = __fdividef(1.f, 1.f + __expf(-a0));            // sigma(i)
        s1v = __fdividef(1.f, 1.f + __expf(-a1));            // sigma(f)
      } else {
        s0v = 1.f - __fdividef(2.f, __expf(2.f * a0) + 1.f); // tanh(g)
        s1v = __fdividef(1.f, 1.f + __expf(-a1));            // sigma(o)
      }
      sbuf[par][w][0][l] = s0v;
      sbuf[par][w][1][l] = s1v;
      lbar2();                              // the ONLY barrier per step
      float o0 = sbuf[par][1 - w][0][l];
      float o1 = sbuf[par][1 - w][1][l];
      float si_, sf, tg, so;
      if (w == 0) { si_ = s0v; sf = s1v; tg = o0;  so = o1;  }
      else        { si_ = o0;  sf = o1;  tg = s0v; so = s1v; }
      c = sf * c + si_ * tg;                // identical FP on both waves
      float tc = 1.f - __fdividef(2.f, __expf(2.f * c) + 1.f);
      float hh = so * tc;
      hsh[w][l] = (__fp16)hh;               // own copy; in-order, no barrier
      yv[i] = hh;
      // sbuf[par] rewritten 2 steps later, after an intervening barrier: safe.
    }
    if (w == 1 && g >= wstart_g) {
#pragma unroll
      for (int i = 0; i < GRP_; ++i) yp[(long)i * ystr] = yv[i];
    }
    yp += GRP_ * ystr;
#pragma unroll
    for (int i = 0; i < GRP_; ++i) { zc[i][0] = zn[i][0]; zc[i][1] = zn[i][1]; }
  }
#else
  // f32 fallback: wave 1 runs the whole chunk alone (no barriers)
  if (w == 1) {
    float wf[256];
#pragma unroll
    for (int i = 0; i < 64; ++i) {
      const int g4 = i >> 4, k4 = i & 15;
      float4 f4 = *reinterpret_cast<const float4*>(&Whh[(size_t)(g4 * 64 + l) * 64 + 4 * k4]);
      wf[g4 * 64 + 4 * k4 + 0] = f4.x; wf[g4 * 64 + 4 * k4 + 1] = f4.y;
      wf[g4 * 64 + 4 * k4 + 2] = f4.z; wf[g4 * 64 + 4 * k4 + 3] = f4.w;
    }
    __shared__ __align__(16) float hs[64];
    hs[l] = 0.f;
    float c = 0.f;
    const long stride = dir ? -256 : 256;
    const long ystr   = dir ? -128 : 128;
    const int sbase = dir ? (N_ - 1 - sw) : sw;
    const ushort_t* p = gx + ((size_t)dir * NN_ + (size_t)b * N_ + sbase) * 256 + l;
    float* yp = y + ((size_t)b * N_ + sbase) * 128 + (size_t)dir * 64 + l;
    const int nsteps = ngroups * GRP_;
    const int wstart = wstart_g * GRP_;
    for (int s = 0; s < nsteps; ++s) {
      float acc[4];
#pragma unroll
      for (int g4 = 0; g4 < 4; ++g4) acc[g4] = bf2f(p[g4 * 64]);
      p += stride;
#pragma unroll
      for (int k4 = 0; k4 < 16; ++k4) {
        float4 hv = *reinterpret_cast<const float4*>(&hs[4 * k4]);
#pragma unroll
        for (int g4 = 0; g4 < 4; ++g4) {
          acc[g4] = fmaf(hv.x, wf[g4*64+4*k4+0], acc[g4]);
          acc[g4] = fmaf(hv.y, wf[g4*64+4*k4+1], acc[g4]);
          acc[g4] = fmaf(hv.z, wf[g4*64+4*k4+2], acc[g4]);
          acc[g4] = fmaf(hv.w, wf[g4*64+4*k4+3], acc[g4]);
        }
      }
      float si_ = __fdividef(1.f, 1.f + __expf(-acc[0]));
      float sf  = __fdividef(1.f, 1.f + __expf(-acc[1]));
      float tg  = 1.f - __fdividef(2.f, __expf(2.f * acc[2]) + 1.f);
      float so  = __fdividef(1.f, 1.f + __expf(-acc[3]));
      c = sf * c + si_ * tg;
      float tc = 1.f - __fdividef(2.f, __expf(2.f * c) + 1.f);
      float hh = so * tc;
      hs[l] = hh;
      if (s >= wstart) *yp = hh;
      yp += ystr;
    }
  }
#endif
}

// ---------------- decoder + masked MSE (block partials, NO atomics) -----------
__global__ __launch_bounds__(256) void k_decoder(
    const float* __restrict__ y, const float* __restrict__ x,
    const float* __restrict__ mask, const float* __restrict__ Wd,
    const float* __restrict__ bd, float* __restrict__ out,
    float2* __restrict__ part) {
  __shared__ float ys[16 * 132];           // 16 rows, padded to 132 floats
  const int tid = threadIdx.x;
  const size_t base = (size_t)blockIdx.x * 2048;
#pragma unroll
  for (int u = 0; u < 2; ++u) {
    int idx = u * 1024 + tid * 4;
    *reinterpret_cast<float4*>(&ys[(idx >> 7) * 132 + (idx & 127)]) =
        *reinterpret_cast<const float4*>(&y[base + idx]);
  }
  __syncthreads();
  size_t v = (size_t)blockIdx.x * 16 + (tid >> 4);
  int f = tid & 15;
  const float* yr = &ys[(tid >> 4) * 132];
  float acc = bd[f];
#pragma unroll
  for (int jj = 0; jj < 128; jj += 4) {
    float4 yv = *reinterpret_cast<const float4*>(&yr[jj]);
    float4 wv = *reinterpret_cast<const float4*>(&Wd[f * 128 + jj]);
    acc = fmaf(yv.x, wv.x, acc); acc = fmaf(yv.y, wv.y, acc);
    acc = fmaf(yv.z, wv.z, acc); acc = fmaf(yv.w, wv.w, acc);
  }
  size_t o = v * 16 + f;
  float xv = x[o], m = mask[o];
  float d = acc - xv;
  out[o] = (m != 0.f) ? xv : acc;
  float num = m * d * d;
  float den = m;
#pragma unroll
  for (int off = 32; off > 0; off >>= 1) {
    num += __shfl_down(num, off);
    den += __shfl_down(den, off);
  }
  __shared__ float2 ps[4];
  if ((tid & 63) == 0) ps[tid >> 6] = make_float2(num, den);
  __syncthreads();
  if (tid == 0) {
    float n = ps[0].x + ps[1].x + ps[2].x + ps[3].x;
    float dd = ps[0].y + ps[1].y + ps[2].y + ps[3].y;
    part[blockIdx.x] = make_float2(n, dd);
  }
}

// ---------------- final loss reduction over 8192 block partials ---------------
__global__ void k_loss2(const float2* __restrict__ part, float* __restrict__ out_loss) {
  const int t = threadIdx.x;
  float n = 0.f, d = 0.f;
  for (int i = t; i < NN_ / 16; i += 256) {
    float2 p = part[i];
    n += p.x; d += p.y;
  }
#pragma unroll
  for (int off = 32; off > 0; off >>= 1) {
    n += __shfl_down(n, off);
    d += __shfl_down(d, off);
  }
  __shared__ float2 ps[4];
  if ((t & 63) == 0) ps[t >> 6] = make_float2(n, d);
  __syncthreads();
  if (t == 0) {
    float nn = ps[0].x + ps[1].x + ps[2].x + ps[3].x;
    float dd = ps[0].y + ps[1].y + ps[2].y + ps[3].y;
    out_loss[0] = nn / (dd + 1e-8f);
  }
}

// ---------------- launch ----------------
extern "C" void kernel_launch(void* const* d_in, const int* in_sizes, int n_in,
                              void* d_out, int out_size, void* d_ws, size_t ws_size,
                              hipStream_t stream) {
  const float* x    = (const float*)d_in[0];
  const int*   ei   = (const int*)d_in[1];   // row = ei, col = ei + E_
  const float* mask = (const float*)d_in[2];
  const float* W1 = (const float*)d_in[3];
  const float* b1 = (const float*)d_in[4];
  const float* W2 = (const float*)d_in[5];
  const float* b2 = (const float*)d_in[6];
  const float* WihF = (const float*)d_in[7];
  const float* WhhF = (const float*)d_in[8];
  const float* bihF = (const float*)d_in[9];
  const float* bhhF = (const float*)d_in[10];
  const float* WihB = (const float*)d_in[11];
  const float* WhhB = (const float*)d_in[12];
  const float* bihB = (const float*)d_in[13];
  const float* bhhB = (const float*)d_in[14];
  const float* Wd = (const float*)d_in[15];
  const float* bd = (const float*)d_in[16];
  float* out = (float*)d_out;

  // layout: dinv | part(64KB) | Y(67M) | C(33.5M f32 agg) | Xb/gx (bf16)
  float*  dinv = (float*)d_ws;
  float2* part = (float2*)(dinv + NN_);
  float*  Y    = (float*)(part + NN_ / 16);
  float*  C    = Y + (size_t)NN_ * 128;
  ushort_t* Xb = (ushort_t*)(C + (size_t)NN_ * 64);
  ushort_t* gx = Xb;   // gx overlays Xb (Xb dead once gates start)
  // sort scratch overlays Y (dead until LSTM writes it)
  int*    srow   = (int*)Y;
  uint_t* cnt    = (uint_t*)(srow + E_);
  uint_t* start  = cnt + NN_;
  uint_t* cursor = start + NN_ + 1;
  uint_t* bsum   = cursor + NN_;

  // ---- degree + col-sort ----
  k_zero<<<NN_ / 256, 256, 0, stream>>>(cnt);
  k_hist<<<E_ / 256, 256, 0, stream>>>(ei + E_, cnt);
  k_dinvc<<<NN_ / 256, 256, 0, stream>>>(cnt, dinv);
  k_bsum<<<512, 256, 0, stream>>>(cnt, bsum);
  k_scan512<<<1, 512, 0, stream>>>(bsum);
  k_scanadd<<<512, 256, 0, stream>>>(cnt, bsum, start, cursor);
  k_place<<<E_ / 256, 256, 0, stream>>>(ei, ei + E_, cursor, srow);

  // ---- GCN layer 1: xws1(bf16) -> Xb, agg1 -> C ----
  k_gemm<FIN_, false><<<NN_ / 4, 256, 0, stream>>>(x, W1, nullptr, dinv, Xb);
  k_colagg<<<NN_ / 4, 256, 0, stream>>>(srow, start, dinv, Xb, C);

  // ---- GCN layer 2: reads C (relu+b1 fused), xws2(bf16) -> Xb, agg2 -> C ----
  k_gemm<64, true><<<NN_ / 4, 256, 0, stream>>>(C, W2, b1, dinv, Xb);
  k_colagg<<<NN_ / 4, 256, 0, stream>>>(srow, start, dinv, Xb, C);

  // ---- gates + chunked LSTM ----
  k_gates<<<2 * (NN_ / 64), 256, 0, stream>>>(C, b2, WihF, bihF, bhhF,
                                              WihB, bihB, bhhB, gx);
  k_lstm4<<<128 * CHK_P, 128, 0, stream>>>(gx, WhhF, WhhB, Y);

  // ---- decoder (block partials) + final loss reduce ----
  k_decoder<<<NN_ / 16, 256, 0, stream>>>(Y, x, mask, Wd, bd, out, part);
  k_loss2<<<1, 256, 0, stream>>>(part, out + (size_t)NN_ * FIN_);
}

// Round 19
// 883.108 us; speedup vs baseline: 1.1275x; 1.1275x over previous
//
#include <hip/hip_runtime.h>

#define NN_ 131072      // T*N
#define T_ 64
#define N_ 2048
#define E_ 2097152
#define FIN_ 16

typedef unsigned short ushort_t;
typedef unsigned int uint_t;

// Clobber-free LDS barrier: no vmcnt drain.
__device__ __forceinline__ void lbar2() {
  __builtin_amdgcn_sched_barrier(0);
  asm volatile("s_waitcnt lgkmcnt(0)");
  __builtin_amdgcn_s_barrier();
  __builtin_amdgcn_sched_barrier(0);
}

__device__ __forceinline__ float bf2f(ushort_t u) {
  return __uint_as_float(((uint_t)u) << 16);
}
__device__ __forceinline__ ushort_t f2bf(float f) {
  uint_t b = __float_as_uint(f);
  b += 0x7fffu + ((b >> 16) & 1u);   // round-to-nearest-even
  return (ushort_t)(b >> 16);
}

#if __has_builtin(__builtin_amdgcn_fdot2)
#define HAVE_DOT2 1
typedef __fp16 half2v __attribute__((ext_vector_type(2)));
__device__ __forceinline__ half2v u2h(uint_t u) { union { uint_t u; half2v h; } x; x.u = u; return x.h; }
__device__ __forceinline__ uint_t h2u(half2v h) { union { uint_t u; half2v h; } x; x.h = h; return x.u; }
#else
#define HAVE_DOT2 0
#endif

// ---------------- histogram of col (1 edge/thread — measured best) -----------
__global__ void k_hist(const int* __restrict__ col, uint_t* __restrict__ cnt) {
  int e = blockIdx.x * 256 + threadIdx.x;
  atomicAdd(&cnt[col[e]], 1u);
}

// ---------------- per-256-chunk sums ----------------
__global__ void k_bsum(const uint_t* __restrict__ cnt, uint_t* __restrict__ bsum) {
  int t = threadIdx.x;
  uint_t v = cnt[blockIdx.x * 256 + t];
  for (int off = 32; off; off >>= 1) v += __shfl_down(v, off);
  __shared__ uint_t s4[4];
  if ((t & 63) == 0) s4[t >> 6] = v;
  __syncthreads();
  if (t == 0) bsum[blockIdx.x] = s4[0] + s4[1] + s4[2] + s4[3];
}

// ---------------- exclusive scan of 512 chunk sums (1 block) ----------------
__global__ void k_scan512(uint_t* __restrict__ bsum) {
  __shared__ uint_t sd[512];
  int t = threadIdx.x;
  uint_t v = bsum[t];
  sd[t] = v;
  __syncthreads();
  for (int off = 1; off < 512; off <<= 1) {
    uint_t x = (t >= off) ? sd[t - off] : 0u;
    __syncthreads();
    sd[t] += x;
    __syncthreads();
  }
  bsum[t] = sd[t] - v;   // exclusive
}

// ---------------- per-chunk exclusive scan + chunk offset + dinv (fused) ------
__global__ void k_scanadd(const uint_t* __restrict__ cnt, const uint_t* __restrict__ bsum,
                          uint_t* __restrict__ start, uint_t* __restrict__ cursor,
                          float* __restrict__ dinv) {
  int t = threadIdx.x;
  int i = blockIdx.x * 256 + t;
  uint_t v = cnt[i];
  dinv[i] = rsqrtf((float)v + 1.f);    // fused: dinv from counts (+self loop)
  __shared__ uint_t sd[256];
  sd[t] = v;
  __syncthreads();
  for (int off = 1; off < 256; off <<= 1) {
    uint_t x = (t >= off) ? sd[t - off] : 0u;
    __syncthreads();
    sd[t] += x;
    __syncthreads();
  }
  uint_t excl = sd[t] - v + bsum[blockIdx.x];
  start[i] = excl;
  cursor[i] = excl;
  if (i == NN_ - 1) start[NN_] = E_;
}

// ---------------- counting-sort placement (1 edge/thread — measured best) -----
__global__ void k_place(const int* __restrict__ row, const int* __restrict__ col,
                        uint_t* __restrict__ cursor, int* __restrict__ srow) {
  int e = blockIdx.x * 256 + threadIdx.x;
  int c = col[e];
  uint_t pos = atomicAdd(&cursor[c], 1u);
  srow[pos] = row[e];
}

// ---------------- GEMM (NN x K) @ (K x 64), dinv-prescaled, bf16 out ---------
template <int K, bool RELU_IN>
__global__ void k_gemm(const float* __restrict__ X, const float* __restrict__ W,
                       const float* __restrict__ bin, const float* __restrict__ dinv,
                       ushort_t* __restrict__ xws) {
  __shared__ float xs[4 * K];
  const int tid = threadIdx.x;
  const int v0 = blockIdx.x * 4;
  for (int t = tid; t < 4 * K; t += 256) {
    float v = X[(size_t)v0 * K + t];
    if (RELU_IN) v = fmaxf(v + bin[t & (K - 1)], 0.f);
    xs[t] = v;
  }
  __syncthreads();
  const int v = v0 + (tid >> 6);
  const int j = tid & 63;
  const float* xr = &xs[(tid >> 6) * K];
  float acc = 0.f;
#pragma unroll
  for (int k = 0; k < K; ++k) acc = fmaf(xr[k], W[k * 64 + j], acc);
  xws[(size_t)v * 64 + j] = f2bf(dinv[v] * acc);
}

// ---------------- column-gather aggregation (bf16 gathers, 8-way ILP) ---------
__global__ void k_colagg(const int* __restrict__ srow, const uint_t* __restrict__ start,
                         const float* __restrict__ dinv, const ushort_t* __restrict__ xws,
                         float* __restrict__ agg) {
  int c = blockIdx.x * 4 + (threadIdx.x >> 6);
  int lane = threadIdx.x & 63;
  uint_t s = start[c], e = start[c + 1];
  float a0 = bf2f(xws[(size_t)c * 64 + lane]);   // self loop
  float a1 = 0.f, a2 = 0.f, a3 = 0.f;
  float a4 = 0.f, a5 = 0.f, a6 = 0.f, a7 = 0.f;
  uint_t i = s;
  for (; i + 8 <= e; i += 8) {
    int r0 = srow[i],     r1 = srow[i + 1], r2 = srow[i + 2], r3 = srow[i + 3];
    int r4 = srow[i + 4], r5 = srow[i + 5], r6 = srow[i + 6], r7 = srow[i + 7];
    a0 += bf2f(xws[(size_t)r0 * 64 + lane]);
    a1 += bf2f(xws[(size_t)r1 * 64 + lane]);
    a2 += bf2f(xws[(size_t)r2 * 64 + lane]);
    a3 += bf2f(xws[(size_t)r3 * 64 + lane]);
    a4 += bf2f(xws[(size_t)r4 * 64 + lane]);
    a5 += bf2f(xws[(size_t)r5 * 64 + lane]);
    a6 += bf2f(xws[(size_t)r6 * 64 + lane]);
    a7 += bf2f(xws[(size_t)r7 * 64 + lane]);
  }
  for (; i < e; ++i) a0 += bf2f(xws[(size_t)srow[i] * 64 + lane]);
  agg[(size_t)c * 64 + lane] =
      dinv[c] * (((a0 + a1) + (a2 + a3)) + ((a4 + a5) + (a6 + a7)));
}

// ---------------- gate-preactivation GEMM (f16 dot2, bf16 out) ----------------
__global__ __launch_bounds__(256) void k_gates(
    const float* __restrict__ A, const float* __restrict__ b2,
    const float* __restrict__ WihF, const float* __restrict__ bihF,
    const float* __restrict__ bhhF,
    const float* __restrict__ WihB, const float* __restrict__ bihB,
    const float* __restrict__ bhhB,
    ushort_t* __restrict__ gx) {
  const int dir = blockIdx.x >> 11;
  const int v0 = (blockIdx.x & 2047) * 64;
  const float* Wih = dir ? WihB : WihF;
  const float* bih = dir ? bihB : bihF;
  const float* bhh = dir ? bhhB : bhhF;
  const int t = threadIdx.x;
  const float bias = bih[t] + bhh[t];

#if HAVE_DOT2
  half2v wp[32];
#pragma unroll
  for (int k4 = 0; k4 < 16; ++k4) {
    float4 f4 = *reinterpret_cast<const float4*>(&Wih[(size_t)t * 64 + 4 * k4]);
    wp[2 * k4]     = __builtin_amdgcn_cvt_pkrtz(f4.x, f4.y);
    wp[2 * k4 + 1] = __builtin_amdgcn_cvt_pkrtz(f4.z, f4.w);
  }
  __shared__ __align__(16) uint_t xs2[64 * 32];   // f16-pair rows, 8 KB
  const float2* A2 = reinterpret_cast<const float2*>(A + (size_t)v0 * 64);
#pragma unroll
  for (int u = 0; u < 8; ++u) {
    int pi = u * 256 + t;
    float2 f = A2[pi];
    int d0 = (2 * pi) & 63;
    float q0 = fmaxf(f.x + b2[d0], 0.f);
    float q1 = fmaxf(f.y + b2[d0 + 1], 0.f);
    xs2[pi] = h2u(__builtin_amdgcn_cvt_pkrtz(q0, q1));
  }
  __syncthreads();
  const uint4* xq = reinterpret_cast<const uint4*>(xs2);
  ushort_t* gp = gx + ((size_t)(dir ? NN_ : 0) + v0) * 256 + t;
  for (int r = 0; r < 64; ++r) {
    float a = bias;
#pragma unroll
    for (int q = 0; q < 8; ++q) {
      uint4 x4 = xq[r * 8 + q];
      a = __builtin_amdgcn_fdot2(wp[4 * q],     u2h(x4.x), a, false);
      a = __builtin_amdgcn_fdot2(wp[4 * q + 1], u2h(x4.y), a, false);
      a = __builtin_amdgcn_fdot2(wp[4 * q + 2], u2h(x4.z), a, false);
      a = __builtin_amdgcn_fdot2(wp[4 * q + 3], u2h(x4.w), a, false);
    }
    gp[(size_t)r * 256] = f2bf(a);
  }
#else
  float w[64];
#pragma unroll
  for (int k = 0; k < 64; k += 4)
    *reinterpret_cast<float4*>(&w[k]) = *reinterpret_cast<const float4*>(&Wih[t * 64 + k]);
  __shared__ float xs[64 * 64];
#pragma unroll
  for (int u = 0; u < 16; ++u) {
    int idx = u * 256 + t;
    xs[idx] = fmaxf(A[(size_t)v0 * 64 + idx] + b2[idx & 63], 0.f);
  }
  __syncthreads();
  ushort_t* gp = gx + ((size_t)(dir ? NN_ : 0) + v0) * 256 + t;
  for (int r = 0; r < 64; ++r) {
    const float* xr = &xs[r * 64];
    float a = bias;
#pragma unroll
    for (int k = 0; k < 64; ++k) a = fmaf(xr[k], w[k], a);
    gp[(size_t)r * 256] = f2bf(a);
  }
#endif
}

// ---------------- persistent LSTM: chunked sequence-parallel (round-17 best) --
// P=32 chunks (C=64, W=32 warm-up). 2 waves: w0 computes sigma(i),sigma(f);
// w1 computes tanh(g),sigma(o), owns c/h. Two barriers/step, VGPR=76.
#define GRP_ 4
#define CHK_P 32
#define CHK_C (N_ / CHK_P)    // 64 steps per chunk
#define CHK_W 32              // warm-up steps

__global__ __launch_bounds__(128, 1) void k_lstm4(
    const ushort_t* __restrict__ gx,
    const float* __restrict__ WhhF, const float* __restrict__ WhhB,
    float* __restrict__ y) {
  const int blk = blockIdx.x;
  const int b     = blk & 63;
  const int dir   = (blk >> 6) & 1;
  const int chunk = blk >> 7;
  const int l   = threadIdx.x & 63;
  const int w   = threadIdx.x >> 6;      // wave id: 0 -> {i,f}, 1 -> {g,o}
  const float* Whh = dir ? WhhB : WhhF;

  const int cstart = chunk * CHK_C;
  const int sw = chunk ? (cstart - CHK_W) : 0;
  const int ngroups = (cstart + CHK_C - sw) / GRP_;
  const int wstart_g = (cstart - sw) / GRP_;   // first group that writes y

#if HAVE_DOT2
  half2v wp[64];
#pragma unroll
  for (int jg = 0; jg < 2; ++jg) {
    const size_t grow = (size_t)((2 * w + jg) * 64 + l) * 64;
#pragma unroll
    for (int k4 = 0; k4 < 16; ++k4) {
      float4 f4 = *reinterpret_cast<const float4*>(&Whh[grow + 4 * k4]);
      wp[jg * 32 + 2 * k4]     = __builtin_amdgcn_cvt_pkrtz(f4.x, f4.y);
      wp[jg * 32 + 2 * k4 + 1] = __builtin_amdgcn_cvt_pkrtz(f4.z, f4.w);
    }
  }
  __shared__ __align__(16) __fp16 hsh[64];
  __shared__ float sbuf[2][64];
  if (w == 1) hsh[l] = (__fp16)0.f;
  float c = 0.f;
  lbar2();                                  // publish hsh init

  const long stride = dir ? -256 : 256;
  const long ystr   = dir ? -128 : 128;
  const int sbase = dir ? (N_ - 1 - sw) : sw;
  const ushort_t* p = gx + ((size_t)dir * NN_ + (size_t)b * N_ + sbase) * 256 + 2 * w * 64 + l;
  float* yp = y + ((size_t)b * N_ + sbase) * 128 + (size_t)dir * 64 + l;

  ushort_t zc[GRP_][2], zn[GRP_][2];
#pragma unroll
  for (int i = 0; i < GRP_; ++i) {
    zc[i][0] = p[i * stride];
    zc[i][1] = p[i * stride + 64];
  }
  p += GRP_ * stride;

  const uint4* hsq = reinterpret_cast<const uint4*>(hsh);

  for (int g = 0; g < ngroups; ++g) {
    if (g != ngroups - 1) {
#pragma unroll
      for (int i = 0; i < GRP_; ++i) {
        zn[i][0] = p[i * stride];
        zn[i][1] = p[i * stride + 64];
      }
    }
    p += GRP_ * stride;

    float yv[GRP_];
#pragma unroll
    for (int i = 0; i < GRP_; ++i) {
      uint_t hu[32];
#pragma unroll
      for (int q = 0; q < 8; ++q) {         // 8 broadcast b128 reads of h
        uint4 hq = hsq[q];
        hu[4*q] = hq.x; hu[4*q+1] = hq.y; hu[4*q+2] = hq.z; hu[4*q+3] = hq.w;
      }
      float a0 = bf2f(zc[i][0]), a1 = bf2f(zc[i][1]);
#pragma unroll
      for (int m = 0; m < 32; ++m) {        // 64 fdot2 per wave
        half2v hm = u2h(hu[m]);
        a0 = __builtin_amdgcn_fdot2(wp[m],      hm, a0, false);
        a1 = __builtin_amdgcn_fdot2(wp[32 + m], hm, a1, false);
      }
      float tg = 0.f, so = 0.f;
      if (w == 0) {
        sbuf[0][l] = __fdividef(1.f, 1.f + __expf(-a0));   // sigma(i)
        sbuf[1][l] = __fdividef(1.f, 1.f + __expf(-a1));   // sigma(f)
      } else {
        tg = 1.f - __fdividef(2.f, __expf(2.f * a0) + 1.f); // tanh(g)
        so = __fdividef(1.f, 1.f + __expf(-a1));            // sigma(o)
      }
      lbar2();                              // A: sbuf published; h reads done
      if (w == 1) {
        float si_ = sbuf[0][l], sf = sbuf[1][l];
        c = sf * c + si_ * tg;
        float tc = 1.f - __fdividef(2.f, __expf(2.f * c) + 1.f);
        float hh = so * tc;
        hsh[l] = (__fp16)hh;
        yv[i] = hh;
      }
      lbar2();                              // B: h(t) published
    }
    if (w == 1 && g >= wstart_g) {
#pragma unroll
      for (int i = 0; i < GRP_; ++i) yp[(long)i * ystr] = yv[i];
    }
    yp += GRP_ * ystr;
#pragma unroll
    for (int i = 0; i < GRP_; ++i) { zc[i][0] = zn[i][0]; zc[i][1] = zn[i][1]; }
  }
#else
  // f32 fallback: wave 1 runs the whole chunk alone (no barriers)
  if (w == 1) {
    float wf[256];
#pragma unroll
    for (int i = 0; i < 64; ++i) {
      const int g4 = i >> 4, k4 = i & 15;
      float4 f4 = *reinterpret_cast<const float4*>(&Whh[(size_t)(g4 * 64 + l) * 64 + 4 * k4]);
      wf[g4 * 64 + 4 * k4 + 0] = f4.x; wf[g4 * 64 + 4 * k4 + 1] = f4.y;
      wf[g4 * 64 + 4 * k4 + 2] = f4.z; wf[g4 * 64 + 4 * k4 + 3] = f4.w;
    }
    __shared__ __align__(16) float hs[64];
    hs[l] = 0.f;
    float c = 0.f;
    const long stride = dir ? -256 : 256;
    const long ystr   = dir ? -128 : 128;
    const int sbase = dir ? (N_ - 1 - sw) : sw;
    const ushort_t* p = gx + ((size_t)dir * NN_ + (size_t)b * N_ + sbase) * 256 + l;
    float* yp = y + ((size_t)b * N_ + sbase) * 128 + (size_t)dir * 64 + l;
    const int nsteps = ngroups * GRP_;
    const int wstart = wstart_g * GRP_;
    for (int s = 0; s < nsteps; ++s) {
      float acc[4];
#pragma unroll
      for (int g4 = 0; g4 < 4; ++g4) acc[g4] = bf2f(p[g4 * 64]);
      p += stride;
#pragma unroll
      for (int k4 = 0; k4 < 16; ++k4) {
        float4 hv = *reinterpret_cast<const float4*>(&hs[4 * k4]);
#pragma unroll
        for (int g4 = 0; g4 < 4; ++g4) {
          acc[g4] = fmaf(hv.x, wf[g4*64+4*k4+0], acc[g4]);
          acc[g4] = fmaf(hv.y, wf[g4*64+4*k4+1], acc[g4]);
          acc[g4] = fmaf(hv.z, wf[g4*64+4*k4+2], acc[g4]);
          acc[g4] = fmaf(hv.w, wf[g4*64+4*k4+3], acc[g4]);
        }
      }
      float si_ = __fdividef(1.f, 1.f + __expf(-acc[0]));
      float sf  = __fdividef(1.f, 1.f + __expf(-acc[1]));
      float tg  = 1.f - __fdividef(2.f, __expf(2.f * acc[2]) + 1.f);
      float so  = __fdividef(1.f, 1.f + __expf(-acc[3]));
      c = sf * c + si_ * tg;
      float tc = 1.f - __fdividef(2.f, __expf(2.f * c) + 1.f);
      float hh = so * tc;
      hs[l] = hh;
      if (s >= wstart) *yp = hh;
      yp += ystr;
    }
  }
#endif
}

// ---------------- decoder + masked MSE (block partials, NO atomics) -----------
__global__ __launch_bounds__(256) void k_decoder(
    const float* __restrict__ y, const float* __restrict__ x,
    const float* __restrict__ mask, const float* __restrict__ Wd,
    const float* __restrict__ bd, float* __restrict__ out,
    float2* __restrict__ part) {
  __shared__ float ys[16 * 132];           // 16 rows, padded to 132 floats
  const int tid = threadIdx.x;
  const size_t base = (size_t)blockIdx.x * 2048;
#pragma unroll
  for (int u = 0; u < 2; ++u) {
    int idx = u * 1024 + tid * 4;
    *reinterpret_cast<float4*>(&ys[(idx >> 7) * 132 + (idx & 127)]) =
        *reinterpret_cast<const float4*>(&y[base + idx]);
  }
  __syncthreads();
  size_t v = (size_t)blockIdx.x * 16 + (tid >> 4);
  int f = tid & 15;
  const float* yr = &ys[(tid >> 4) * 132];
  float acc = bd[f];
#pragma unroll
  for (int jj = 0; jj < 128; jj += 4) {
    float4 yv = *reinterpret_cast<const float4*>(&yr[jj]);
    float4 wv = *reinterpret_cast<const float4*>(&Wd[f * 128 + jj]);
    acc = fmaf(yv.x, wv.x, acc); acc = fmaf(yv.y, wv.y, acc);
    acc = fmaf(yv.z, wv.z, acc); acc = fmaf(yv.w, wv.w, acc);
  }
  size_t o = v * 16 + f;
  float xv = x[o], m = mask[o];
  float d = acc - xv;
  out[o] = (m != 0.f) ? xv : acc;
  float num = m * d * d;
  float den = m;
#pragma unroll
  for (int off = 32; off > 0; off >>= 1) {
    num += __shfl_down(num, off);
    den += __shfl_down(den, off);
  }
  __shared__ float2 ps[4];
  if ((tid & 63) == 0) ps[tid >> 6] = make_float2(num, den);
  __syncthreads();
  if (tid == 0) {
    float n = ps[0].x + ps[1].x + ps[2].x + ps[3].x;
    float dd = ps[0].y + ps[1].y + ps[2].y + ps[3].y;
    part[blockIdx.x] = make_float2(n, dd);
  }
}

// ---------------- final loss reduction over 8192 block partials ---------------
__global__ void k_loss2(const float2* __restrict__ part, float* __restrict__ out_loss) {
  const int t = threadIdx.x;
  float n = 0.f, d = 0.f;
  for (int i = t; i < NN_ / 16; i += 256) {
    float2 p = part[i];
    n += p.x; d += p.y;
  }
#pragma unroll
  for (int off = 32; off > 0; off >>= 1) {
    n += __shfl_down(n, off);
    d += __shfl_down(d, off);
  }
  __shared__ float2 ps[4];
  if ((t & 63) == 0) ps[t >> 6] = make_float2(n, d);
  __syncthreads();
  if (t == 0) {
    float nn = ps[0].x + ps[1].x + ps[2].x + ps[3].x;
    float dd = ps[0].y + ps[1].y + ps[2].y + ps[3].y;
    out_loss[0] = nn / (dd + 1e-8f);
  }
}

// ---------------- launch ----------------
extern "C" void kernel_launch(void* const* d_in, const int* in_sizes, int n_in,
                              void* d_out, int out_size, void* d_ws, size_t ws_size,
                              hipStream_t stream) {
  const float* x    = (const float*)d_in[0];
  const int*   ei   = (const int*)d_in[1];   // row = ei, col = ei + E_
  const float* mask = (const float*)d_in[2];
  const float* W1 = (const float*)d_in[3];
  const float* b1 = (const float*)d_in[4];
  const float* W2 = (const float*)d_in[5];
  const float* b2 = (const float*)d_in[6];
  const float* WihF = (const float*)d_in[7];
  const float* WhhF = (const float*)d_in[8];
  const float* bihF = (const float*)d_in[9];
  const float* bhhF = (const float*)d_in[10];
  const float* WihB = (const float*)d_in[11];
  const float* WhhB = (const float*)d_in[12];
  const float* bihB = (const float*)d_in[13];
  const float* bhhB = (const float*)d_in[14];
  const float* Wd = (const float*)d_in[15];
  const float* bd = (const float*)d_in[16];
  float* out = (float*)d_out;

  // layout: dinv | part(64KB) | Y(67M) | C(33.5M f32 agg) | Xb/gx (bf16)
  float*  dinv = (float*)d_ws;
  float2* part = (float2*)(dinv + NN_);
  float*  Y    = (float*)(part + NN_ / 16);
  float*  C    = Y + (size_t)NN_ * 128;
  ushort_t* Xb = (ushort_t*)(C + (size_t)NN_ * 64);
  ushort_t* gx = Xb;   // gx overlays Xb (Xb dead once gates start)
  // sort scratch overlays Y (dead until LSTM writes it)
  int*    srow   = (int*)Y;
  uint_t* cnt    = (uint_t*)(srow + E_);
  uint_t* start  = cnt + NN_;
  uint_t* cursor = start + NN_ + 1;
  uint_t* bsum   = cursor + NN_;

  // ---- degree + col-sort ----
  hipMemsetAsync(cnt, 0, NN_ * sizeof(uint_t), stream);
  k_hist<<<E_ / 256, 256, 0, stream>>>(ei + E_, cnt);
  k_bsum<<<512, 256, 0, stream>>>(cnt, bsum);
  k_scan512<<<1, 512, 0, stream>>>(bsum);
  k_scanadd<<<512, 256, 0, stream>>>(cnt, bsum, start, cursor, dinv);
  k_place<<<E_ / 256, 256, 0, stream>>>(ei, ei + E_, cursor, srow);

  // ---- GCN layer 1: xws1(bf16) -> Xb, agg1 -> C ----
  k_gemm<FIN_, false><<<NN_ / 4, 256, 0, stream>>>(x, W1, nullptr, dinv, Xb);
  k_colagg<<<NN_ / 4, 256, 0, stream>>>(srow, start, dinv, Xb, C);

  // ---- GCN layer 2: reads C (relu+b1 fused), xws2(bf16) -> Xb, agg2 -> C ----
  k_gemm<64, true><<<NN_ / 4, 256, 0, stream>>>(C, W2, b1, dinv, Xb);
  k_colagg<<<NN_ / 4, 256, 0, stream>>>(srow, start, dinv, Xb, C);

  // ---- gates + chunked LSTM ----
  k_gates<<<2 * (NN_ / 64), 256, 0, stream>>>(C, b2, WihF, bihF, bhhF,
                                              WihB, bihB, bhhB, gx);
  k_lstm4<<<128 * CHK_P, 128, 0, stream>>>(gx, WhhF, WhhB, Y);

  // ---- decoder (block partials) + final loss reduce ----
  k_decoder<<<NN_ / 16, 256, 0, stream>>>(Y, x, mask, Wd, bd, out, part);
  k_loss2<<<1, 256, 0, stream>>>(part, out + (size_t)NN_ * FIN_);
}